// Round 3
// baseline (990.507 us; speedup 1.0000x reference)
//
#include <hip/hip_runtime.h>
#include <hip/hip_bf16.h>
#include <math.h>

#define D_MODEL 256
#define D_STATE 16
#define D_INNER 512
#define DT_RANK 16
#define NB 4
#define NVAR 32
#define SEG 96
#define TOKENS (NB*NVAR*SEG)   /* 12288 */

typedef float f4 __attribute__((ext_vector_type(4)));

__device__ __forceinline__ float silu_f(float x) { return x / (1.0f + __expf(-x)); }

// ---------------------------------------------------------------------------
// Stage a BNx32 fp32 W-tile into LDS via global_load_lds width 16.
// LDS linear [row][32]; SOURCE column pre-swizzled: LDS word row*32+kq holds
// G[row][kq ^ sw(row)], sw(row) = ((row>>2)&7)<<2.  Reads XOR the same way.
// ---------------------------------------------------------------------------
template<int BN, int K, int NTHR>
__device__ __forceinline__ void stageW(const float* __restrict__ g,
                                       float* lds, int tid, int k0)
{
    constexpr int SIT = (BN * 8) / NTHR;   // 16B units per thread
#pragma unroll
    for (int r = 0; r < SIT; r++) {
        int idx = r * NTHR + tid;          // 16B-unit index
        int row = idx >> 3;
        int kq  = (idx & 7) << 2;
        int col = kq ^ (((row >> 2) & 7) << 2);
        int ub  = __builtin_amdgcn_readfirstlane((idx & ~63) << 2);
        __builtin_amdgcn_global_load_lds(
            (const __attribute__((address_space(1))) void*)(g + (size_t)row * K + k0 + col),
            (__attribute__((address_space(3))) void*)(lds + ub), 16, 0, 0);
    }
}

// ---------------------------------------------------------------------------
// NT GEMM, A read DIRECT from global (16-lane-broadcast fragments, L1-hot),
// W staged in double-buffered swizzled LDS.  C[m,n] = sum_k A[m,k]*W[n,k].
// Microtile TM x TN per thread as f4 chunks.  Requires TM==8 (two row
// halves), TN in {4,8}, BK=32, K % 32 == 0, tiles full.
// MODE 0: plain.  MODE 2: rows (b,v,s)->(b,s,v).  MODE 3: inverse.
// ---------------------------------------------------------------------------
template<int BM, int BN, int K, int NTHR, int TN, int MODE>
__global__ __launch_bounds__(NTHR, 3)
void gemm_dA(const float* __restrict__ A, const float* __restrict__ W,
             float* __restrict__ C, int N)
{
    constexpr int TM = 8;
    constexpr int CW = BN / TN;            // 16 threads across cols
    __shared__ float smem[2 * BN * 32];

    const int tid = threadIdx.x;
    const int m0 = blockIdx.x * BM;
    const int n0 = blockIdx.y * BN;
    const int tx = tid % CW;
    const int ty = tid / CW;

    // W byte-offset bases (bits disjoint: row<<7 | sw<<4), XOR k-quad byte.
    int pW[TN];
#pragma unroll
    for (int cj = 0; cj < TN / 4; cj++)
#pragma unroll
        for (int jj = 0; jj < 4; jj++) {
            int c = cj * (BN / 2) + tx * 4 + jj;
            pW[cj * 4 + jj] = (c << 7) | (((c >> 2) & 7) << 4);
        }

    // A row pointers (broadcast across 16 lanes of same ty)
    const float* ap[TM];
#pragma unroll
    for (int hi = 0; hi < 2; hi++)
#pragma unroll
        for (int ii = 0; ii < 4; ii++)
            ap[hi * 4 + ii] = A + (size_t)(m0 + hi * (BM / 2) + ty * 4 + ii) * K;

    float acc[TM][TN];
#pragma unroll
    for (int i = 0; i < TM; i++)
#pragma unroll
        for (int j = 0; j < TN; j++) acc[i][j] = 0.0f;

    const float* Wg = W + (size_t)n0 * K;
    float* Ws0 = smem;
    float* Ws1 = smem + BN * 32;

    stageW<BN, K, NTHR>(Wg, Ws0, tid, 0);

    constexpr int NT = K / 32;
    for (int t = 0; t < NT; t++) {
        __syncthreads();                   // W tile t resident (vmcnt drained)
        const bool odd = t & 1;
        const char* Wb = (const char*)(odd ? Ws1 : Ws0);
        if (t + 1 < NT)
            stageW<BN, K, NTHR>(Wg, odd ? Ws0 : Ws1, tid, (t + 1) * 32);
#pragma unroll
        for (int q = 0; q < 8; q++) {
            const int kb = q << 4;         // byte offset of k-quad in LDS row
            f4 av[TM], wv[TN];
#pragma unroll
            for (int i = 0; i < TM; i++)
                av[i] = *(const f4*)(ap[i] + t * 32 + q * 4);
#pragma unroll
            for (int j = 0; j < TN; j++)
                wv[j] = *(const f4*)(Wb + (pW[j] ^ kb));
#pragma unroll
            for (int i = 0; i < TM; i++)
#pragma unroll
                for (int j = 0; j < TN; j++)
#pragma unroll
                    for (int qq = 0; qq < 4; qq++)
                        acc[i][j] = fmaf(av[i][qq], wv[j][qq], acc[i][j]);
        }
    }

#pragma unroll
    for (int hi = 0; hi < 2; hi++)
#pragma unroll
        for (int ii = 0; ii < 4; ii++) {
            int m = m0 + hi * (BM / 2) + ty * 4 + ii;
            int orow = m;
            if (MODE == 2) {               // (b*32+v)*96+s -> (b*96+s)*32+v
                int b = m / 3072, rr = m % 3072;
                int v = rr / 96, s = rr % 96;
                orow = (b * 96 + s) * 32 + v;
            } else if (MODE == 3) {        // (b*96+s)*32+v -> (b*32+v)*96+s
                int b = m / 3072, rr = m % 3072;
                int s = rr / 32, v = rr % 32;
                orow = (b * 32 + v) * 96 + s;
            }
            float* crow = C + (size_t)orow * N + n0;
            int i = hi * 4 + ii;
#pragma unroll
            for (int cj = 0; cj < TN / 4; cj++) {
                f4 v;
                v[0] = acc[i][cj * 4 + 0];
                v[1] = acc[i][cj * 4 + 1];
                v[2] = acc[i][cj * 4 + 2];
                v[3] = acc[i][cj * 4 + 3];
                *(f4*)(crow + cj * (BN / 2) + tx * 4) = v;
            }
        }
}

// ---------------------------------------------------------------------------
// Small tiled NT GEMM (x_proj N=48, dt_proj K=16).
// MODE 0: plain.  MODE 1: softplus(acc + bias[n]).
// ---------------------------------------------------------------------------
template<int BM, int BN, int BK, int TM, int TN, int MODE>
__global__ __launch_bounds__(256)
void gemm_nt(const float* __restrict__ A, int lda,
             const float* __restrict__ W,
             float* __restrict__ C,
             const float* __restrict__ bias,
             int M, int N, int K)
{
    __shared__ float As[BK][BM + 4];
    __shared__ float Ws[BK][BN + 4];

    const int tid = threadIdx.x;
    const int tx  = tid % (BN / TN);
    const int ty  = tid / (BN / TN);
    const int m0  = blockIdx.x * BM;
    const int n0  = blockIdx.y * BN;

    float acc[TM][TN];
#pragma unroll
    for (int i = 0; i < TM; i++)
#pragma unroll
        for (int j = 0; j < TN; j++) acc[i][j] = 0.0f;

    constexpr int AF4 = (BM * BK) / 1024;
    constexpr int WF4 = (BN * BK) / 1024;
    constexpr int F4R = BK / 4;

    for (int k0 = 0; k0 < K; k0 += BK) {
#pragma unroll
        for (int c = 0; c < AF4; c++) {
            int idx = tid + c * 256;
            int row = idx / F4R;
            int kc  = (idx % F4R) * 4;
            float4 v = *(const float4*)(A + (size_t)(m0 + row) * lda + k0 + kc);
            As[kc + 0][row] = v.x;
            As[kc + 1][row] = v.y;
            As[kc + 2][row] = v.z;
            As[kc + 3][row] = v.w;
        }
#pragma unroll
        for (int c = 0; c < WF4; c++) {
            int idx = tid + c * 256;
            int row = idx / F4R;
            int kc  = (idx % F4R) * 4;
            float4 v;
            if (n0 + row < N) v = *(const float4*)(W + (size_t)(n0 + row) * K + k0 + kc);
            else              v = make_float4(0.f, 0.f, 0.f, 0.f);
            Ws[kc + 0][row] = v.x;
            Ws[kc + 1][row] = v.y;
            Ws[kc + 2][row] = v.z;
            Ws[kc + 3][row] = v.w;
        }
        __syncthreads();

#pragma unroll
        for (int kk = 0; kk < BK; kk++) {
            float a[TM], w[TN];
#pragma unroll
            for (int i = 0; i < TM; i++) a[i] = As[kk][ty * TM + i];
#pragma unroll
            for (int j = 0; j < TN; j++) w[j] = Ws[kk][tx * TN + j];
#pragma unroll
            for (int i = 0; i < TM; i++)
#pragma unroll
                for (int j = 0; j < TN; j++)
                    acc[i][j] = fmaf(a[i], w[j], acc[i][j]);
        }
        __syncthreads();
    }

#pragma unroll
    for (int i = 0; i < TM; i++) {
        int m = m0 + ty * TM + i;
#pragma unroll
        for (int j = 0; j < TN; j++) {
            int n = n0 + tx * TN + j;
            if (n < N) {
                float v = acc[i][j];
                if (MODE == 1) {
                    v += bias[n];
                    v = (v > 20.0f) ? v : log1pf(__expf(v));
                }
                C[(size_t)m * N + n] = v;
            }
        }
    }
}

// ---------------------------------------------------------------------------
// Depthwise causal conv (width 4) + bias + SiLU.
// ---------------------------------------------------------------------------
__global__ __launch_bounds__(256)
void conv_silu(const float* __restrict__ xz, const float* __restrict__ cw,
               const float* __restrict__ cb, float* __restrict__ xc, int L)
{
    int i = blockIdx.x * 256 + threadIdx.x;
    int e = i % D_INNER;
    int t = i / D_INNER;
    int l = t % L;
    float acc = cb[e];
#pragma unroll
    for (int j = 0; j < 4; j++) {
        int li = l - 3 + j;
        if (li >= 0) acc = fmaf(xz[(size_t)(t + li - l) * 1024 + e], cw[e * 4 + j], acc);
    }
    xc[i] = silu_f(acc);
}

// ---------------------------------------------------------------------------
// Selective scan + skip + gate.  One thread per (bn, channel e).
// ---------------------------------------------------------------------------
__global__ __launch_bounds__(256)
void scan_gate(float* __restrict__ dty,
               const float* __restrict__ xc,
               const float* __restrict__ xz,
               const float* __restrict__ dbl,
               const float* __restrict__ A_log,
               const float* __restrict__ Dvec,
               int L)
{
    int bn = blockIdx.x >> 1;
    int e  = ((blockIdx.x & 1) << 8) + threadIdx.x;

    float Ae[D_STATE], h[D_STATE];
#pragma unroll
    for (int s = 0; s < D_STATE; s++) {
        Ae[s] = -__expf(A_log[e * D_STATE + s]);
        h[s]  = 0.0f;
    }
    const float De = Dvec[e];

    for (int l = 0; l < L; l++) {
        int tk = bn * L + l;
        float dtv = dty[(size_t)tk * 512 + e];
        float u   = xc [(size_t)tk * 512 + e];
        float zv  = xz [(size_t)tk * 1024 + 512 + e];
        const float* bc = dbl + (size_t)tk * 48;
        float y = 0.0f;
#pragma unroll
        for (int s = 0; s < D_STATE; s++) {
            float dA = __expf(dtv * Ae[s]);
            h[s] = fmaf(dA, h[s], dtv * bc[16 + s] * u);
            y    = fmaf(h[s], bc[32 + s], y);
        }
        dty[(size_t)tk * 512 + e] = (y + u * De) * silu_f(zv);
    }
}

// ---------------------------------------------------------------------------
// One mamba stage.
// ---------------------------------------------------------------------------
template<int OUTMODE>
static void run_stage(const float* xin,
                      const float* in_w, const float* conv_w, const float* conv_b,
                      const float* xproj_w, const float* dt_w, const float* dt_b,
                      const float* A_log, const float* Dvec, const float* out_w,
                      float* xz, float* xc, float* dbl, float* dty, float* outp,
                      int Bn, int L, hipStream_t stream)
{
    const int M = TOKENS;
    // in_proj: [M,1024] = x[M,256] * in_w^T   (A direct, W in LDS)
    gemm_dA<128, 128, 256, 256, 8, 0><<<dim3(M / 128, 1024 / 128), 256, 0, stream>>>(
        xin, in_w, xz, 1024);
    // conv + silu
    conv_silu<<<dim3((M * D_INNER) / 256), 256, 0, stream>>>(xz, conv_w, conv_b, xc, L);
    // x_proj: [M,48] = xc[M,512] * xproj_w^T
    gemm_nt<64,64,16,4,4,0><<<dim3(M / 64, 1), 256, 0, stream>>>(
        xc, 512, xproj_w, dbl, nullptr, M, 48, 512);
    // dt_proj + softplus
    gemm_nt<128,64,16,8,4,1><<<dim3(M / 128, 512 / 64), 256, 0, stream>>>(
        dbl, 48, dt_w, dty, dt_b, M, 512, 16);
    // scan + skip + gate
    scan_gate<<<dim3(Bn * 2), 256, 0, stream>>>(dty, xc, xz, dbl, A_log, Dvec, L);
    // out_proj with fused layout transpose: 64x64 tiles, 768 blocks
    gemm_dA<64, 64, 512, 128, 4, OUTMODE><<<dim3(M / 64, 256 / 64), 128, 0, stream>>>(
        dty, out_w, outp, 256);
}

extern "C" void kernel_launch(void* const* d_in, const int* in_sizes, int n_in,
                              void* d_out, int out_size, void* d_ws, size_t ws_size,
                              hipStream_t stream)
{
    const float* x = (const float*)d_in[0];
    const float* t_in_w    = (const float*)d_in[1];
    const float* t_conv_w  = (const float*)d_in[2];
    const float* t_conv_b  = (const float*)d_in[3];
    const float* t_xproj_w = (const float*)d_in[4];
    const float* t_dt_w    = (const float*)d_in[5];
    const float* t_dt_b    = (const float*)d_in[6];
    const float* t_A_log   = (const float*)d_in[7];
    const float* t_D       = (const float*)d_in[8];
    const float* t_out_w   = (const float*)d_in[9];
    const float* d_in_w    = (const float*)d_in[10];
    const float* d_conv_w  = (const float*)d_in[11];
    const float* d_conv_b  = (const float*)d_in[12];
    const float* d_xproj_w = (const float*)d_in[13];
    const float* d_dt_w    = (const float*)d_in[14];
    const float* d_dt_b    = (const float*)d_in[15];
    const float* d_A_log   = (const float*)d_in[16];
    const float* d_D       = (const float*)d_in[17];
    const float* d_out_w   = (const float*)d_in[18];

    float* ws  = (float*)d_ws;
    float* xz  = ws;
    float* xc  = xz  + (size_t)TOKENS * 1024;
    float* dbl = xc  + (size_t)TOKENS * 512;
    float* dty = dbl + (size_t)TOKENS * 48;
    float* xt  = dty + (size_t)TOKENS * 512;
    const size_t need_bytes = ((size_t)TOKENS * (1024 + 512 + 48 + 512 + 256)) * 4;
    if (ws_size < need_bytes) return;

    // stage 1: time scan, Bn = 128, L = 96
    run_stage<2>(x, t_in_w, t_conv_w, t_conv_b, t_xproj_w, t_dt_w, t_dt_b,
                 t_A_log, t_D, t_out_w, xz, xc, dbl, dty, xt,
                 NB * NVAR, SEG, stream);
    // stage 2: dimension scan, Bn = 384, L = 32
    run_stage<3>(xt, d_in_w, d_conv_w, d_conv_b, d_xproj_w, d_dt_w, d_dt_b,
                 d_A_log, d_D, d_out_w, xz, xc, dbl, dty, (float*)d_out,
                 NB * SEG, NVAR, stream);
}

// Round 4
// 549.944 us; speedup vs baseline: 1.8011x; 1.8011x over previous
//
#include <hip/hip_runtime.h>
#include <hip/hip_bf16.h>
#include <math.h>

#define D_MODEL 256
#define D_STATE 16
#define D_INNER 512
#define DT_RANK 16
#define NB 4
#define NVAR 32
#define SEG 96
#define TOKENS (NB*NVAR*SEG)   /* 12288 */

typedef float f4 __attribute__((ext_vector_type(4)));

__device__ __forceinline__ float silu_f(float x) { return x / (1.0f + __expf(-x)); }

// ---------------------------------------------------------------------------
// NT GEMM: C[m,n] = sum_k A[m,k] * W[n,k].
// Block = 256 threads = 4 waves. BM=32 (wave w owns rows w*8..w*8+7, all 64
// lanes share the A fragment -> scalar/SMEM loads). BN=256 (lane owns cols
// 4*lane..4*lane+3). W staged k-major in LDS (lds[k][col]): one conflict-free
// ds_read_b128 per k feeds 32 FMA -> 2 FMA/LDS-byte, FMA-bound.
// BK=16 double-buffered (32 KB) -> 4-5 blocks/CU.
// MODE 0: plain store.  MODE 2: rows (b,v,s)->(b,s,v).  MODE 3: inverse.
// ---------------------------------------------------------------------------
template<int K, int MODE>
__global__ __launch_bounds__(256, 4)
void gemm_sma(const float* __restrict__ A, const float* __restrict__ W,
              float* __restrict__ C, int N)
{
    constexpr int NT = K / 16;
    __shared__ float lds[2 * 4096];      // 2 x [16][256]
    const int tid  = threadIdx.x;
    const int lane = tid & 63;
    const int wid  = __builtin_amdgcn_readfirstlane(tid >> 6);
    const int m0 = blockIdx.x * 32;
    const int n0 = blockIdx.y * 256;

    const int s_col = tid >> 2;          // 0..63  (col group, +64*uu)
    const int s_kc  = (tid & 3) << 2;    // 0,4,8,12 (k chunk)

    // wave-uniform A row pointers -> scalar loads
    const float* arow[8];
#pragma unroll
    for (int i = 0; i < 8; i++)
        arow[i] = A + (size_t)(m0 + wid * 8 + i) * K;

    const float* Wg = W + (size_t)n0 * K;

    f4 acc[8];
#pragma unroll
    for (int i = 0; i < 8; i++) acc[i] = (f4)0.0f;

    f4 wreg[4];
    // prologue: stage tile 0
#pragma unroll
    for (int uu = 0; uu < 4; uu++)
        wreg[uu] = *(const f4*)(Wg + (size_t)(uu * 64 + s_col) * K + s_kc);
#pragma unroll
    for (int uu = 0; uu < 4; uu++)
#pragma unroll
        for (int e = 0; e < 4; e++)
            lds[(s_kc + e) * 256 + uu * 64 + s_col] = wreg[uu][e];
    __syncthreads();

    for (int t = 0; t < NT; t++) {
        const int k0 = t * 16;
        if (t + 1 < NT) {                // issue next-tile loads early (T14)
#pragma unroll
            for (int uu = 0; uu < 4; uu++)
                wreg[uu] = *(const f4*)(Wg + (size_t)(uu * 64 + s_col) * K + k0 + 16 + s_kc);
        }
        const float* buf = lds + (t & 1) * 4096;
#pragma unroll
        for (int kq = 0; kq < 4; kq++) {
            f4 a4[8];
#pragma unroll
            for (int i = 0; i < 8; i++)
                a4[i] = *(const f4*)(arow[i] + k0 + kq * 4);   // uniform -> s_load
#pragma unroll
            for (int ke = 0; ke < 4; ke++) {
                f4 wv = *(const f4*)(buf + (kq * 4 + ke) * 256 + lane * 4);
#pragma unroll
                for (int i = 0; i < 8; i++)
#pragma unroll
                    for (int c = 0; c < 4; c++)
                        acc[i][c] = fmaf(a4[i][ke], wv[c], acc[i][c]);
            }
        }
        if (t + 1 < NT) {                // write-late into the other buffer
            float* nb = lds + ((t + 1) & 1) * 4096;
#pragma unroll
            for (int uu = 0; uu < 4; uu++)
#pragma unroll
                for (int e = 0; e < 4; e++)
                    nb[(s_kc + e) * 256 + uu * 64 + s_col] = wreg[uu][e];
        }
        __syncthreads();
    }

#pragma unroll
    for (int i = 0; i < 8; i++) {
        int m = m0 + wid * 8 + i;
        int orow = m;
        if (MODE == 2) {                 // (b*32+v)*96+s -> (b*96+s)*32+v
            int b = m / 3072, rr = m % 3072;
            int v = rr / 96, s = rr % 96;
            orow = (b * 96 + s) * 32 + v;
        } else if (MODE == 3) {          // (b*96+s)*32+v -> (b*32+v)*96+s
            int b = m / 3072, rr = m % 3072;
            int s = rr / 32, v = rr % 32;
            orow = (b * 32 + v) * 96 + s;
        }
        *(f4*)(C + (size_t)orow * N + n0 + lane * 4) = acc[i];
    }
}

// ---------------------------------------------------------------------------
// Small tiled NT GEMM (x_proj N=48, dt_proj K=16).
// MODE 0: plain.  MODE 1: softplus(acc + bias[n]).
// ---------------------------------------------------------------------------
template<int BM, int BN, int BK, int TM, int TN, int MODE>
__global__ __launch_bounds__(256)
void gemm_nt(const float* __restrict__ A, int lda,
             const float* __restrict__ W,
             float* __restrict__ C,
             const float* __restrict__ bias,
             int M, int N, int K)
{
    __shared__ float As[BK][BM + 4];
    __shared__ float Ws[BK][BN + 4];

    const int tid = threadIdx.x;
    const int tx  = tid % (BN / TN);
    const int ty  = tid / (BN / TN);
    const int m0  = blockIdx.x * BM;
    const int n0  = blockIdx.y * BN;

    float acc[TM][TN];
#pragma unroll
    for (int i = 0; i < TM; i++)
#pragma unroll
        for (int j = 0; j < TN; j++) acc[i][j] = 0.0f;

    constexpr int AF4 = (BM * BK) / 1024;
    constexpr int WF4 = (BN * BK) / 1024;
    constexpr int F4R = BK / 4;

    for (int k0 = 0; k0 < K; k0 += BK) {
#pragma unroll
        for (int c = 0; c < AF4; c++) {
            int idx = tid + c * 256;
            int row = idx / F4R;
            int kc  = (idx % F4R) * 4;
            float4 v = *(const float4*)(A + (size_t)(m0 + row) * lda + k0 + kc);
            As[kc + 0][row] = v.x;
            As[kc + 1][row] = v.y;
            As[kc + 2][row] = v.z;
            As[kc + 3][row] = v.w;
        }
#pragma unroll
        for (int c = 0; c < WF4; c++) {
            int idx = tid + c * 256;
            int row = idx / F4R;
            int kc  = (idx % F4R) * 4;
            float4 v;
            if (n0 + row < N) v = *(const float4*)(W + (size_t)(n0 + row) * K + k0 + kc);
            else              v = make_float4(0.f, 0.f, 0.f, 0.f);
            Ws[kc + 0][row] = v.x;
            Ws[kc + 1][row] = v.y;
            Ws[kc + 2][row] = v.z;
            Ws[kc + 3][row] = v.w;
        }
        __syncthreads();

#pragma unroll
        for (int kk = 0; kk < BK; kk++) {
            float a[TM], w[TN];
#pragma unroll
            for (int i = 0; i < TM; i++) a[i] = As[kk][ty * TM + i];
#pragma unroll
            for (int j = 0; j < TN; j++) w[j] = Ws[kk][tx * TN + j];
#pragma unroll
            for (int i = 0; i < TM; i++)
#pragma unroll
                for (int j = 0; j < TN; j++)
                    acc[i][j] = fmaf(a[i], w[j], acc[i][j]);
        }
        __syncthreads();
    }

#pragma unroll
    for (int i = 0; i < TM; i++) {
        int m = m0 + ty * TM + i;
#pragma unroll
        for (int j = 0; j < TN; j++) {
            int n = n0 + tx * TN + j;
            if (n < N) {
                float v = acc[i][j];
                if (MODE == 1) {
                    v += bias[n];
                    v = (v > 20.0f) ? v : log1pf(__expf(v));
                }
                C[(size_t)m * N + n] = v;
            }
        }
    }
}

// ---------------------------------------------------------------------------
// Depthwise causal conv (width 4) + bias + SiLU.
// ---------------------------------------------------------------------------
__global__ __launch_bounds__(256)
void conv_silu(const float* __restrict__ xz, const float* __restrict__ cw,
               const float* __restrict__ cb, float* __restrict__ xc, int L)
{
    int i = blockIdx.x * 256 + threadIdx.x;
    int e = i % D_INNER;
    int t = i / D_INNER;
    int l = t % L;
    float acc = cb[e];
#pragma unroll
    for (int j = 0; j < 4; j++) {
        int li = l - 3 + j;
        if (li >= 0) acc = fmaf(xz[(size_t)(t + li - l) * 1024 + e], cw[e * 4 + j], acc);
    }
    xc[i] = silu_f(acc);
}

// ---------------------------------------------------------------------------
// Selective scan + skip + gate.  One thread per (bn, channel e).
// ---------------------------------------------------------------------------
__global__ __launch_bounds__(256)
void scan_gate(float* __restrict__ dty,
               const float* __restrict__ xc,
               const float* __restrict__ xz,
               const float* __restrict__ dbl,
               const float* __restrict__ A_log,
               const float* __restrict__ Dvec,
               int L)
{
    int bn = blockIdx.x >> 1;
    int e  = ((blockIdx.x & 1) << 8) + threadIdx.x;

    float Ae[D_STATE], h[D_STATE];
#pragma unroll
    for (int s = 0; s < D_STATE; s++) {
        Ae[s] = -__expf(A_log[e * D_STATE + s]);
        h[s]  = 0.0f;
    }
    const float De = Dvec[e];

    for (int l = 0; l < L; l++) {
        int tk = bn * L + l;
        float dtv = dty[(size_t)tk * 512 + e];
        float u   = xc [(size_t)tk * 512 + e];
        float zv  = xz [(size_t)tk * 1024 + 512 + e];
        const float* bc = dbl + (size_t)tk * 48;
        float y = 0.0f;
#pragma unroll
        for (int s = 0; s < D_STATE; s++) {
            float dA = __expf(dtv * Ae[s]);
            h[s] = fmaf(dA, h[s], dtv * bc[16 + s] * u);
            y    = fmaf(h[s], bc[32 + s], y);
        }
        dty[(size_t)tk * 512 + e] = (y + u * De) * silu_f(zv);
    }
}

// ---------------------------------------------------------------------------
// One mamba stage.
// ---------------------------------------------------------------------------
template<int OUTMODE>
static void run_stage(const float* xin,
                      const float* in_w, const float* conv_w, const float* conv_b,
                      const float* xproj_w, const float* dt_w, const float* dt_b,
                      const float* A_log, const float* Dvec, const float* out_w,
                      float* xz, float* xc, float* dbl, float* dty, float* outp,
                      int Bn, int L, hipStream_t stream)
{
    const int M = TOKENS;
    // in_proj: [M,1024] = x[M,256] * in_w^T
    gemm_sma<256, 0><<<dim3(M / 32, 1024 / 256), 256, 0, stream>>>(xin, in_w, xz, 1024);
    // conv + silu
    conv_silu<<<dim3((M * D_INNER) / 256), 256, 0, stream>>>(xz, conv_w, conv_b, xc, L);
    // x_proj: [M,48] = xc[M,512] * xproj_w^T
    gemm_nt<64,64,16,4,4,0><<<dim3(M / 64, 1), 256, 0, stream>>>(
        xc, 512, xproj_w, dbl, nullptr, M, 48, 512);
    // dt_proj + softplus
    gemm_nt<128,64,16,8,4,1><<<dim3(M / 128, 512 / 64), 256, 0, stream>>>(
        dbl, 48, dt_w, dty, dt_b, M, 512, 16);
    // scan + skip + gate
    scan_gate<<<dim3(Bn * 2), 256, 0, stream>>>(dty, xc, xz, dbl, A_log, Dvec, L);
    // out_proj with fused layout transpose
    gemm_sma<512, OUTMODE><<<dim3(M / 32, 256 / 256), 256, 0, stream>>>(dty, out_w, outp, 256);
}

extern "C" void kernel_launch(void* const* d_in, const int* in_sizes, int n_in,
                              void* d_out, int out_size, void* d_ws, size_t ws_size,
                              hipStream_t stream)
{
    const float* x = (const float*)d_in[0];
    const float* t_in_w    = (const float*)d_in[1];
    const float* t_conv_w  = (const float*)d_in[2];
    const float* t_conv_b  = (const float*)d_in[3];
    const float* t_xproj_w = (const float*)d_in[4];
    const float* t_dt_w    = (const float*)d_in[5];
    const float* t_dt_b    = (const float*)d_in[6];
    const float* t_A_log   = (const float*)d_in[7];
    const float* t_D       = (const float*)d_in[8];
    const float* t_out_w   = (const float*)d_in[9];
    const float* d_in_w    = (const float*)d_in[10];
    const float* d_conv_w  = (const float*)d_in[11];
    const float* d_conv_b  = (const float*)d_in[12];
    const float* d_xproj_w = (const float*)d_in[13];
    const float* d_dt_w    = (const float*)d_in[14];
    const float* d_dt_b    = (const float*)d_in[15];
    const float* d_A_log   = (const float*)d_in[16];
    const float* d_D       = (const float*)d_in[17];
    const float* d_out_w   = (const float*)d_in[18];

    float* ws  = (float*)d_ws;
    float* xz  = ws;
    float* xc  = xz  + (size_t)TOKENS * 1024;
    float* dbl = xc  + (size_t)TOKENS * 512;
    float* dty = dbl + (size_t)TOKENS * 48;
    float* xt  = dty + (size_t)TOKENS * 512;
    const size_t need_bytes = ((size_t)TOKENS * (1024 + 512 + 48 + 512 + 256)) * 4;
    if (ws_size < need_bytes) return;

    // stage 1: time scan, Bn = 128, L = 96
    run_stage<2>(x, t_in_w, t_conv_w, t_conv_b, t_xproj_w, t_dt_w, t_dt_b,
                 t_A_log, t_D, t_out_w, xz, xc, dbl, dty, xt,
                 NB * NVAR, SEG, stream);
    // stage 2: dimension scan, Bn = 384, L = 32
    run_stage<3>(xt, d_in_w, d_conv_w, d_conv_b, d_xproj_w, d_dt_w, d_dt_b,
                 d_A_log, d_D, d_out_w, xz, xc, dbl, dty, (float*)d_out,
                 NB * SEG, NVAR, stream);
}